// Round 1
// baseline (1372.057 us; speedup 1.0000x reference)
//
#include <hip/hip_runtime.h>
#include <hip/hip_bf16.h>

#define N_NODES 100000
#define N_EDGES 3200000
#define CH 128
#define NG 128
#define BN_EPS 1e-5f

// ---------------- degree histogram ----------------
__global__ __launch_bounds__(256) void k_deg(const int* __restrict__ dst, int* __restrict__ deg) {
    int i = blockIdx.x * 256 + threadIdx.x;
    if (i < N_EDGES) atomicAdd(&deg[dst[i]], 1);
}

__global__ __launch_bounds__(256) void k_dinv(const int* __restrict__ deg, float* __restrict__ dinv) {
    int i = blockIdx.x * 256 + threadIdx.x;
    if (i < N_NODES) dinv[i] = rsqrtf((float)(deg[i] + 1));  // +1 self loop
}

// ---------------- exclusive scan of deg -> offs (3 kernels) ----------------
// 1024 items / block, 98 blocks
__global__ __launch_bounds__(256) void k_scanA(const int* __restrict__ deg, int* __restrict__ bsum) {
    __shared__ int sm[256];
    int base = blockIdx.x * 1024;
    int t = threadIdx.x;
    int idx = base + t * 4;
    int s = 0;
    if (idx < N_NODES) {  // N_NODES % 4 == 0 -> all-or-nothing
        int4 v = *(const int4*)&deg[idx];
        s = v.x + v.y + v.z + v.w;
    }
    sm[t] = s;
    __syncthreads();
    for (int off = 128; off > 0; off >>= 1) {
        if (t < off) sm[t] += sm[t + off];
        __syncthreads();
    }
    if (t == 0) bsum[blockIdx.x] = sm[0];
}

__global__ void k_scanB(int* __restrict__ bsum) {
    if (threadIdx.x == 0) {
        int run = 0;
        for (int b = 0; b < 98; ++b) { int v = bsum[b]; bsum[b] = run; run += v; }
    }
}

__global__ __launch_bounds__(256) void k_scanC(const int* __restrict__ deg, const int* __restrict__ bsum,
                                               int* __restrict__ offs) {
    __shared__ int sm[256];
    int base = blockIdx.x * 1024;
    int t = threadIdx.x;
    int idx = base + t * 4;
    int4 v = make_int4(0, 0, 0, 0);
    if (idx < N_NODES) v = *(const int4*)&deg[idx];
    int tsum = v.x + v.y + v.z + v.w;
    sm[t] = tsum;
    __syncthreads();
    // Hillis-Steele inclusive scan over 256 thread sums
    for (int off = 1; off < 256; off <<= 1) {
        int val = sm[t];
        int add = (t >= off) ? sm[t - off] : 0;
        __syncthreads();
        sm[t] = val + add;
        __syncthreads();
    }
    int excl = sm[t] - tsum + bsum[blockIdx.x];
    if (idx + 0 < N_NODES) offs[idx + 0] = excl;
    if (idx + 1 < N_NODES) offs[idx + 1] = excl + v.x;
    if (idx + 2 < N_NODES) offs[idx + 2] = excl + v.x + v.y;
    if (idx + 3 < N_NODES) offs[idx + 3] = excl + v.x + v.y + v.z;
}

// ---------------- CSR fill (counting sort by dst) ----------------
__global__ __launch_bounds__(256) void k_fill(const int* __restrict__ src, const int* __restrict__ dst,
                                              const int* __restrict__ offs, int* __restrict__ cur,
                                              int* __restrict__ perm) {
    int e = blockIdx.x * 256 + threadIdx.x;
    if (e < N_EDGES) {
        int d = dst[e];
        int pos = offs[d] + atomicAdd(&cur[d], 1);
        perm[pos] = src[e];
    }
}

// ---------------- fp32 GEMM: Y[nrows,128] = X[nrows,128] @ W[128,128] ----------------
// block: 256 threads, 64 rows/block, full 128 cols, K=128 staged transposed in LDS
__global__ __launch_bounds__(256) void k_gemm(const float* __restrict__ X, const float* __restrict__ W,
                                              float* __restrict__ Y, int nrows) {
    __shared__ float xsT[128 * 64];  // [k][r]
    int row0 = blockIdx.x * 64;
    int t = threadIdx.x;
    {
        int r = t >> 2, q = t & 3;
        int grow = row0 + r;
        const float4* srcp = (const float4*)&X[(size_t)grow * CH + q * 32];
        #pragma unroll
        for (int i = 0; i < 8; ++i) {
            float4 v = make_float4(0.f, 0.f, 0.f, 0.f);
            if (grow < nrows) v = srcp[i];
            int c = q * 32 + i * 4;
            xsT[(c + 0) * 64 + r] = v.x;
            xsT[(c + 1) * 64 + r] = v.y;
            xsT[(c + 2) * 64 + r] = v.z;
            xsT[(c + 3) * 64 + r] = v.w;
        }
    }
    __syncthreads();
    int tx = t & 15, ty = t >> 4;  // cols tx*8..+7, rows ty*4..+3
    float acc[4][8];
    #pragma unroll
    for (int i = 0; i < 4; ++i)
        #pragma unroll
        for (int j = 0; j < 8; ++j) acc[i][j] = 0.f;

    const float4* xs4 = (const float4*)xsT;  // xs4[k*16 + rgroup]
    #pragma unroll 4
    for (int k = 0; k < 128; ++k) {
        float4 a = xs4[k * 16 + ty];
        float4 w0 = *(const float4*)&W[k * CH + tx * 8];
        float4 w1 = *(const float4*)&W[k * CH + tx * 8 + 4];
        float av[4] = {a.x, a.y, a.z, a.w};
        float wv[8] = {w0.x, w0.y, w0.z, w0.w, w1.x, w1.y, w1.z, w1.w};
        #pragma unroll
        for (int i = 0; i < 4; ++i)
            #pragma unroll
            for (int j = 0; j < 8; ++j) acc[i][j] += av[i] * wv[j];
    }
    #pragma unroll
    for (int i = 0; i < 4; ++i) {
        int grow = row0 + ty * 4 + i;
        if (grow < nrows) {
            float4 o0 = make_float4(acc[i][0], acc[i][1], acc[i][2], acc[i][3]);
            float4 o1 = make_float4(acc[i][4], acc[i][5], acc[i][6], acc[i][7]);
            *(float4*)&Y[(size_t)grow * CH + tx * 8] = o0;
            *(float4*)&Y[(size_t)grow * CH + tx * 8 + 4] = o1;
        }
    }
}

// ---------------- SpMM layer 1: aggregate + bias + BN + ReLU ----------------
// one wave per node row; lane handles channels 2*lane, 2*lane+1
__global__ __launch_bounds__(256) void k_spmm_bn_relu(
    const float* __restrict__ xw, const int* __restrict__ perm, const int* __restrict__ offs,
    const int* __restrict__ deg, const float* __restrict__ dinv, const float* __restrict__ bias,
    const float* __restrict__ gamma, const float* __restrict__ beta,
    const float* __restrict__ rmean, const float* __restrict__ rvar, float* __restrict__ out) {
    int wave = blockIdx.x * 4 + (threadIdx.x >> 6);
    int row = __builtin_amdgcn_readfirstlane(wave);
    if (row >= N_NODES) return;
    int lane = threadIdx.x & 63;
    const float2* xw2 = (const float2*)xw;
    float di = dinv[row];
    float2 a = xw2[(size_t)row * 64 + lane];
    float ax = di * di * a.x, ay = di * di * a.y;
    int beg = offs[row];
    int end = beg + deg[row];
    int j = beg;
    for (; j + 4 <= end; j += 4) {
        int s0 = perm[j], s1 = perm[j + 1], s2 = perm[j + 2], s3 = perm[j + 3];
        float c0 = di * dinv[s0], c1 = di * dinv[s1], c2 = di * dinv[s2], c3 = di * dinv[s3];
        float2 v0 = xw2[(size_t)s0 * 64 + lane];
        float2 v1 = xw2[(size_t)s1 * 64 + lane];
        float2 v2 = xw2[(size_t)s2 * 64 + lane];
        float2 v3 = xw2[(size_t)s3 * 64 + lane];
        ax += c0 * v0.x + c1 * v1.x + c2 * v2.x + c3 * v3.x;
        ay += c0 * v0.y + c1 * v1.y + c2 * v2.y + c3 * v3.y;
    }
    for (; j < end; ++j) {
        int s = perm[j];
        float c = di * dinv[s];
        float2 v = xw2[(size_t)s * 64 + lane];
        ax += c * v.x;
        ay += c * v.y;
    }
    int c0 = lane * 2;
    float2 b = *(const float2*)&bias[c0];
    float2 g = *(const float2*)&gamma[c0];
    float2 be = *(const float2*)&beta[c0];
    float2 rm = *(const float2*)&rmean[c0];
    float2 rv = *(const float2*)&rvar[c0];
    float sx = g.x * rsqrtf(rv.x + BN_EPS);
    float sy = g.y * rsqrtf(rv.y + BN_EPS);
    float vx = (ax + b.x - rm.x) * sx + be.x;
    float vy = (ay + b.y - rm.y) * sy + be.y;
    float2 o;
    o.x = fmaxf(vx, 0.f);
    o.y = fmaxf(vy, 0.f);
    ((float2*)out)[(size_t)row * 64 + lane] = o;
}

// ---------------- SpMM layer 2: aggregate + bias + pooled-sum atomics ----------------
__global__ __launch_bounds__(256) void k_spmm_pool(
    const float* __restrict__ xw, const int* __restrict__ perm, const int* __restrict__ offs,
    const int* __restrict__ deg, const float* __restrict__ dinv, const float* __restrict__ bias,
    const int* __restrict__ batch, float* __restrict__ psum, int* __restrict__ pcnt) {
    int wave = blockIdx.x * 4 + (threadIdx.x >> 6);
    int row = __builtin_amdgcn_readfirstlane(wave);
    if (row >= N_NODES) return;
    int lane = threadIdx.x & 63;
    const float2* xw2 = (const float2*)xw;
    float di = dinv[row];
    float2 a = xw2[(size_t)row * 64 + lane];
    float ax = di * di * a.x, ay = di * di * a.y;
    int beg = offs[row];
    int end = beg + deg[row];
    int j = beg;
    for (; j + 4 <= end; j += 4) {
        int s0 = perm[j], s1 = perm[j + 1], s2 = perm[j + 2], s3 = perm[j + 3];
        float c0 = di * dinv[s0], c1 = di * dinv[s1], c2 = di * dinv[s2], c3 = di * dinv[s3];
        float2 v0 = xw2[(size_t)s0 * 64 + lane];
        float2 v1 = xw2[(size_t)s1 * 64 + lane];
        float2 v2 = xw2[(size_t)s2 * 64 + lane];
        float2 v3 = xw2[(size_t)s3 * 64 + lane];
        ax += c0 * v0.x + c1 * v1.x + c2 * v2.x + c3 * v3.x;
        ay += c0 * v0.y + c1 * v1.y + c2 * v2.y + c3 * v3.y;
    }
    for (; j < end; ++j) {
        int s = perm[j];
        float c = di * dinv[s];
        float2 v = xw2[(size_t)s * 64 + lane];
        ax += c * v.x;
        ay += c * v.y;
    }
    int c0 = lane * 2;
    float2 b = *(const float2*)&bias[c0];
    float vx = ax + b.x, vy = ay + b.y;
    int g = batch[row];
    unsafeAtomicAdd(&psum[g * CH + c0], vx);
    unsafeAtomicAdd(&psum[g * CH + c0 + 1], vy);
    if (lane == 0) atomicAdd(&pcnt[g], 1);
}

// ---------------- head: pooled mean -> FC(relu) -> classifier ----------------
__global__ __launch_bounds__(128) void k_head(const float* __restrict__ psum, const int* __restrict__ pcnt,
                                              const float* __restrict__ fw1, const float* __restrict__ fb1,
                                              const float* __restrict__ cw, const float* __restrict__ cb,
                                              float* __restrict__ out) {
    __shared__ float fws[128 * 64];
    for (int i = threadIdx.x; i < 128 * 64; i += 128) fws[i] = fw1[i];
    __syncthreads();
    int g = threadIdx.x;  // 128 graphs, 128 threads
    float z[64];
    #pragma unroll
    for (int j = 0; j < 64; ++j) z[j] = fb1[j];
    float cnt = fmaxf((float)pcnt[g], 1.f);
    float inv = 1.f / cnt;
    for (int c = 0; c < 128; ++c) {
        float p = psum[g * CH + c] * inv;
        #pragma unroll
        for (int j = 0; j < 64; ++j) z[j] += p * fws[c * 64 + j];
    }
    float o0 = cb[0], o1 = cb[1];
    #pragma unroll
    for (int j = 0; j < 64; ++j) {
        float zz = fmaxf(z[j], 0.f);
        o0 += zz * cw[j * 2];
        o1 += zz * cw[j * 2 + 1];
    }
    out[g * 2] = o0;
    out[g * 2 + 1] = o1;
}

extern "C" void kernel_launch(void* const* d_in, const int* in_sizes, int n_in,
                              void* d_out, int out_size, void* d_ws, size_t ws_size,
                              hipStream_t stream) {
    const float* x     = (const float*)d_in[0];
    const int*   ei    = (const int*)d_in[1];
    const int*   batch = (const int*)d_in[2];
    const float* W1    = (const float*)d_in[3];
    const float* b1    = (const float*)d_in[4];
    const float* gamma = (const float*)d_in[5];
    const float* beta  = (const float*)d_in[6];
    const float* rmean = (const float*)d_in[7];
    const float* rvar  = (const float*)d_in[8];
    const float* W2    = (const float*)d_in[9];
    const float* b2    = (const float*)d_in[10];
    const float* fw1   = (const float*)d_in[11];
    const float* fb1   = (const float*)d_in[12];
    const float* cw    = (const float*)d_in[13];
    const float* cb    = (const float*)d_in[14];
    const int* srcp = ei;
    const int* dstp = ei + N_EDGES;

    char* w = (char*)d_ws;
    int*   deg  = (int*)w;   w += 400000;
    int*   cur  = (int*)w;   w += 400000;
    float* psum = (float*)w; w += 65536;
    int*   pcnt = (int*)w;   w += 512;
    size_t zbytes = 400000 + 400000 + 65536 + 512;
    int*   offs = (int*)w;   w += 400000;
    float* dinv = (float*)w; w += 400000;
    int*   bsum = (int*)w;   w += 4096;
    int*   perm = (int*)w;   w += 12800000;
    float* bufA = (float*)w; w += 51200000;
    float* bufB = (float*)w; w += 51200000;

    hipMemsetAsync(d_ws, 0, zbytes, stream);
    k_deg<<<12500, 256, 0, stream>>>(dstp, deg);
    k_dinv<<<391, 256, 0, stream>>>(deg, dinv);
    k_scanA<<<98, 256, 0, stream>>>(deg, bsum);
    k_scanB<<<1, 64, 0, stream>>>(bsum);
    k_scanC<<<98, 256, 0, stream>>>(deg, bsum, offs);
    k_fill<<<12500, 256, 0, stream>>>(srcp, dstp, offs, cur, perm);
    k_gemm<<<1563, 256, 0, stream>>>(x, W1, bufA, N_NODES);
    k_spmm_bn_relu<<<25000, 256, 0, stream>>>(bufA, perm, offs, deg, dinv, b1, gamma, beta, rmean, rvar, bufB);
    k_gemm<<<1563, 256, 0, stream>>>(bufB, W2, bufA, N_NODES);
    k_spmm_pool<<<25000, 256, 0, stream>>>(bufA, perm, offs, deg, dinv, b2, batch, psum, pcnt);
    k_head<<<1, 128, 0, stream>>>(psum, pcnt, fw1, fb1, cw, cb, (float*)d_out);
}

// Round 2
// 921.939 us; speedup vs baseline: 1.4882x; 1.4882x over previous
//
#include <hip/hip_runtime.h>
#include <hip/hip_bf16.h>

#define N_NODES 100000
#define N_EDGES 3200000
#define CH 128
#define NG 128
#define BN_EPS 1e-5f

__device__ __forceinline__ float bflo(unsigned int u) { return __uint_as_float(u << 16); }
__device__ __forceinline__ float bfhi(unsigned int u) { return __uint_as_float(u & 0xffff0000u); }
__device__ __forceinline__ unsigned int f2bf(float f) {  // RNE
    unsigned int u = __float_as_uint(f);
    return (u + 0x7fffu + ((u >> 16) & 1u)) >> 16;
}
__device__ __forceinline__ unsigned int pack2bf(float x, float y) {
    return f2bf(x) | (f2bf(y) << 16);
}

// ---------------- degree histogram ----------------
__global__ __launch_bounds__(256) void k_deg(const int* __restrict__ dst, int* __restrict__ deg) {
    int i = blockIdx.x * 256 + threadIdx.x;
    if (i < N_EDGES) atomicAdd(&deg[dst[i]], 1);
}

__global__ __launch_bounds__(256) void k_dinv(const int* __restrict__ deg, float* __restrict__ dinv) {
    int i = blockIdx.x * 256 + threadIdx.x;
    if (i < N_NODES) dinv[i] = rsqrtf((float)(deg[i] + 1));  // +1 self loop
}

// ---------------- exclusive scan of deg -> offs ----------------
__global__ __launch_bounds__(256) void k_scanA(const int* __restrict__ deg, int* __restrict__ bsum) {
    __shared__ int sm[256];
    int base = blockIdx.x * 1024;
    int t = threadIdx.x;
    int idx = base + t * 4;
    int s = 0;
    if (idx < N_NODES) {
        int4 v = *(const int4*)&deg[idx];
        s = v.x + v.y + v.z + v.w;
    }
    sm[t] = s;
    __syncthreads();
    for (int off = 128; off > 0; off >>= 1) {
        if (t < off) sm[t] += sm[t + off];
        __syncthreads();
    }
    if (t == 0) bsum[blockIdx.x] = sm[0];
}

__global__ void k_scanB(int* __restrict__ bsum) {
    if (threadIdx.x == 0) {
        int run = 0;
        for (int b = 0; b < 98; ++b) { int v = bsum[b]; bsum[b] = run; run += v; }
    }
}

__global__ __launch_bounds__(256) void k_scanC(const int* __restrict__ deg, const int* __restrict__ bsum,
                                               int* __restrict__ offs) {
    __shared__ int sm[256];
    int base = blockIdx.x * 1024;
    int t = threadIdx.x;
    int idx = base + t * 4;
    int4 v = make_int4(0, 0, 0, 0);
    if (idx < N_NODES) v = *(const int4*)&deg[idx];
    int tsum = v.x + v.y + v.z + v.w;
    sm[t] = tsum;
    __syncthreads();
    for (int off = 1; off < 256; off <<= 1) {
        int val = sm[t];
        int add = (t >= off) ? sm[t - off] : 0;
        __syncthreads();
        sm[t] = val + add;
        __syncthreads();
    }
    int excl = sm[t] - tsum + bsum[blockIdx.x];
    if (idx + 0 < N_NODES) offs[idx + 0] = excl;
    if (idx + 1 < N_NODES) offs[idx + 1] = excl + v.x;
    if (idx + 2 < N_NODES) offs[idx + 2] = excl + v.x + v.y;
    if (idx + 3 < N_NODES) offs[idx + 3] = excl + v.x + v.y + v.z;
}

// ---------------- CSR fill (counting sort by dst) ----------------
__global__ __launch_bounds__(256) void k_fill(const int* __restrict__ src, const int* __restrict__ dst,
                                              const int* __restrict__ offs, int* __restrict__ cur,
                                              int* __restrict__ perm) {
    int e = blockIdx.x * 256 + threadIdx.x;
    if (e < N_EDGES) {
        int d = dst[e];
        int pos = offs[d] + atomicAdd(&cur[d], 1);
        perm[pos] = src[e];
    }
}

// ---------------- GEMM: Y_bf16[nrows,128] = X[nrows,128] @ W[128,128] ----------------
// X fp32 (BF16IN=0) or bf16-packed (BF16IN=1); fp32 accumulate; bf16 output.
template <int BF16IN>
__global__ __launch_bounds__(256) void k_gemm(const void* __restrict__ Xv, const float* __restrict__ W,
                                              unsigned int* __restrict__ Yb, int nrows) {
    __shared__ float xsT[128 * 64];  // [k][r]
    int row0 = blockIdx.x * 64;
    int t = threadIdx.x;
    {
        int r = t >> 2, q = t & 3;  // thread covers channels q*32..q*32+31 of row r
        int grow = row0 + r;
        bool ok = grow < nrows;
        if (BF16IN) {
            const uint2* srcp = (const uint2*)((const unsigned int*)Xv + (size_t)grow * 64 + q * 16);
            #pragma unroll
            for (int i = 0; i < 8; ++i) {
                uint2 u = ok ? srcp[i] : make_uint2(0, 0);
                int c = q * 32 + i * 4;
                xsT[(c + 0) * 64 + r] = bflo(u.x);
                xsT[(c + 1) * 64 + r] = bfhi(u.x);
                xsT[(c + 2) * 64 + r] = bflo(u.y);
                xsT[(c + 3) * 64 + r] = bfhi(u.y);
            }
        } else {
            const float4* srcp = (const float4*)((const float*)Xv + (size_t)grow * CH + q * 32);
            #pragma unroll
            for (int i = 0; i < 8; ++i) {
                float4 v = ok ? srcp[i] : make_float4(0.f, 0.f, 0.f, 0.f);
                int c = q * 32 + i * 4;
                xsT[(c + 0) * 64 + r] = v.x;
                xsT[(c + 1) * 64 + r] = v.y;
                xsT[(c + 2) * 64 + r] = v.z;
                xsT[(c + 3) * 64 + r] = v.w;
            }
        }
    }
    __syncthreads();
    int tx = t & 15, ty = t >> 4;  // cols tx*8..+7, rows ty*4..+3
    float acc[4][8];
    #pragma unroll
    for (int i = 0; i < 4; ++i)
        #pragma unroll
        for (int j = 0; j < 8; ++j) acc[i][j] = 0.f;

    const float4* xs4 = (const float4*)xsT;
    #pragma unroll 4
    for (int k = 0; k < 128; ++k) {
        float4 a = xs4[k * 16 + ty];
        float4 w0 = *(const float4*)&W[k * CH + tx * 8];
        float4 w1 = *(const float4*)&W[k * CH + tx * 8 + 4];
        float av[4] = {a.x, a.y, a.z, a.w};
        float wv[8] = {w0.x, w0.y, w0.z, w0.w, w1.x, w1.y, w1.z, w1.w};
        #pragma unroll
        for (int i = 0; i < 4; ++i)
            #pragma unroll
            for (int j = 0; j < 8; ++j) acc[i][j] += av[i] * wv[j];
    }
    #pragma unroll
    for (int i = 0; i < 4; ++i) {
        int grow = row0 + ty * 4 + i;
        if (grow < nrows) {
            unsigned int o[4];
            #pragma unroll
            for (int j = 0; j < 4; ++j) o[j] = pack2bf(acc[i][2 * j], acc[i][2 * j + 1]);
            *(uint4*)&Yb[(size_t)grow * 64 + tx * 4] = *(uint4*)o;
        }
    }
}

// ---------------- SpMM layer 1: aggregate + bias + BN + ReLU -> bf16 ----------------
// one wave per node row; lane handles channels 2*lane, 2*lane+1 (bf16x2 packed)
__global__ __launch_bounds__(256) void k_spmm_bn_relu(
    const unsigned int* __restrict__ xwb, const int* __restrict__ perm, const int* __restrict__ offs,
    const int* __restrict__ deg, const float* __restrict__ dinv, const float* __restrict__ bias,
    const float* __restrict__ gamma, const float* __restrict__ beta,
    const float* __restrict__ rmean, const float* __restrict__ rvar, unsigned int* __restrict__ outb) {
    int wave = blockIdx.x * 4 + (threadIdx.x >> 6);
    int row = __builtin_amdgcn_readfirstlane(wave);
    if (row >= N_NODES) return;
    int lane = threadIdx.x & 63;
    float di = dinv[row];
    unsigned int a = xwb[(size_t)row * 64 + lane];
    float ax = di * di * bflo(a), ay = di * di * bfhi(a);
    int beg = offs[row];
    int end = beg + deg[row];
    int j = beg;
    for (; j + 8 <= end; j += 8) {
        int s[8];
        #pragma unroll
        for (int q = 0; q < 8; ++q) s[q] = perm[j + q];
        float c[8];
        #pragma unroll
        for (int q = 0; q < 8; ++q) c[q] = di * dinv[s[q]];
        unsigned int v[8];
        #pragma unroll
        for (int q = 0; q < 8; ++q) v[q] = xwb[(size_t)s[q] * 64 + lane];
        #pragma unroll
        for (int q = 0; q < 8; ++q) { ax += c[q] * bflo(v[q]); ay += c[q] * bfhi(v[q]); }
    }
    for (; j < end; ++j) {
        int s = perm[j];
        float c = di * dinv[s];
        unsigned int v = xwb[(size_t)s * 64 + lane];
        ax += c * bflo(v);
        ay += c * bfhi(v);
    }
    int c0 = lane * 2;
    float2 b = *(const float2*)&bias[c0];
    float2 g = *(const float2*)&gamma[c0];
    float2 be = *(const float2*)&beta[c0];
    float2 rm = *(const float2*)&rmean[c0];
    float2 rv = *(const float2*)&rvar[c0];
    float sx = g.x * rsqrtf(rv.x + BN_EPS);
    float sy = g.y * rsqrtf(rv.y + BN_EPS);
    float vx = fmaxf((ax + b.x - rm.x) * sx + be.x, 0.f);
    float vy = fmaxf((ay + b.y - rm.y) * sy + be.y, 0.f);
    outb[(size_t)row * 64 + lane] = pack2bf(vx, vy);
}

// ---------------- SpMM layer 2: aggregate + bias + pooled-sum (block-reduced atomics) ----------------
__global__ __launch_bounds__(256) void k_spmm_pool(
    const unsigned int* __restrict__ xwb, const int* __restrict__ perm, const int* __restrict__ offs,
    const int* __restrict__ deg, const float* __restrict__ dinv, const float* __restrict__ bias,
    const int* __restrict__ batch, float* __restrict__ psum, int* __restrict__ pcnt) {
    __shared__ float red[4][128];
    __shared__ int gid[4];
    int w = threadIdx.x >> 6;
    int row = __builtin_amdgcn_readfirstlane(blockIdx.x * 4 + w);  // grid exactly covers N_NODES
    int lane = threadIdx.x & 63;
    float di = dinv[row];
    unsigned int a = xwb[(size_t)row * 64 + lane];
    float ax = di * di * bflo(a), ay = di * di * bfhi(a);
    int beg = offs[row];
    int end = beg + deg[row];
    int j = beg;
    for (; j + 8 <= end; j += 8) {
        int s[8];
        #pragma unroll
        for (int q = 0; q < 8; ++q) s[q] = perm[j + q];
        float c[8];
        #pragma unroll
        for (int q = 0; q < 8; ++q) c[q] = di * dinv[s[q]];
        unsigned int v[8];
        #pragma unroll
        for (int q = 0; q < 8; ++q) v[q] = xwb[(size_t)s[q] * 64 + lane];
        #pragma unroll
        for (int q = 0; q < 8; ++q) { ax += c[q] * bflo(v[q]); ay += c[q] * bfhi(v[q]); }
    }
    for (; j < end; ++j) {
        int s = perm[j];
        float c = di * dinv[s];
        unsigned int v = xwb[(size_t)s * 64 + lane];
        ax += c * bflo(v);
        ay += c * bfhi(v);
    }
    int c0 = lane * 2;
    float2 b = *(const float2*)&bias[c0];
    float vx = ax + b.x, vy = ay + b.y;
    int g = batch[row];
    red[w][c0] = vx;
    red[w][c0 + 1] = vy;
    if (lane == 0) gid[w] = g;
    __syncthreads();
    bool same = (gid[0] == gid[1]) && (gid[1] == gid[2]) && (gid[2] == gid[3]);
    if (same) {
        if (w == 0) {
            float sx = red[0][c0] + red[1][c0] + red[2][c0] + red[3][c0];
            float sy = red[0][c0 + 1] + red[1][c0 + 1] + red[2][c0 + 1] + red[3][c0 + 1];
            unsafeAtomicAdd(&psum[gid[0] * CH + c0], sx);
            unsafeAtomicAdd(&psum[gid[0] * CH + c0 + 1], sy);
            if (lane == 0) atomicAdd(&pcnt[gid[0]], 4);
        }
    } else {
        unsafeAtomicAdd(&psum[g * CH + c0], vx);
        unsafeAtomicAdd(&psum[g * CH + c0 + 1], vy);
        if (lane == 0) atomicAdd(&pcnt[g], 1);
    }
}

// ---------------- head: pooled mean -> FC(relu) -> classifier ----------------
__global__ __launch_bounds__(128) void k_head(const float* __restrict__ psum, const int* __restrict__ pcnt,
                                              const float* __restrict__ fw1, const float* __restrict__ fb1,
                                              const float* __restrict__ cw, const float* __restrict__ cb,
                                              float* __restrict__ out) {
    __shared__ float fws[128 * 64];
    for (int i = threadIdx.x; i < 128 * 64; i += 128) fws[i] = fw1[i];
    __syncthreads();
    int g = threadIdx.x;
    float z[64];
    #pragma unroll
    for (int j = 0; j < 64; ++j) z[j] = fb1[j];
    float cnt = fmaxf((float)pcnt[g], 1.f);
    float inv = 1.f / cnt;
    for (int c = 0; c < 128; ++c) {
        float p = psum[g * CH + c] * inv;
        #pragma unroll
        for (int j = 0; j < 64; ++j) z[j] += p * fws[c * 64 + j];
    }
    float o0 = cb[0], o1 = cb[1];
    #pragma unroll
    for (int j = 0; j < 64; ++j) {
        float zz = fmaxf(z[j], 0.f);
        o0 += zz * cw[j * 2];
        o1 += zz * cw[j * 2 + 1];
    }
    out[g * 2] = o0;
    out[g * 2 + 1] = o1;
}

extern "C" void kernel_launch(void* const* d_in, const int* in_sizes, int n_in,
                              void* d_out, int out_size, void* d_ws, size_t ws_size,
                              hipStream_t stream) {
    const float* x     = (const float*)d_in[0];
    const int*   ei    = (const int*)d_in[1];
    const int*   batch = (const int*)d_in[2];
    const float* W1    = (const float*)d_in[3];
    const float* b1    = (const float*)d_in[4];
    const float* gamma = (const float*)d_in[5];
    const float* beta  = (const float*)d_in[6];
    const float* rmean = (const float*)d_in[7];
    const float* rvar  = (const float*)d_in[8];
    const float* W2    = (const float*)d_in[9];
    const float* b2    = (const float*)d_in[10];
    const float* fw1   = (const float*)d_in[11];
    const float* fb1   = (const float*)d_in[12];
    const float* cw    = (const float*)d_in[13];
    const float* cb    = (const float*)d_in[14];
    const int* srcp = ei;
    const int* dstp = ei + N_EDGES;

    char* w = (char*)d_ws;
    int*   deg  = (int*)w;   w += 400000;
    int*   cur  = (int*)w;   w += 400000;
    float* psum = (float*)w; w += 65536;
    int*   pcnt = (int*)w;   w += 512;
    size_t zbytes = 400000 + 400000 + 65536 + 512;
    int*   offs = (int*)w;   w += 400000;
    float* dinv = (float*)w; w += 400000;
    int*   bsum = (int*)w;   w += 4096;
    int*   perm = (int*)w;   w += 12800000;
    unsigned int* bufA = (unsigned int*)w; w += 25600000;  // bf16x2 [100k,64]
    unsigned int* bufB = (unsigned int*)w; w += 25600000;  // bf16x2 [100k,64]

    hipMemsetAsync(d_ws, 0, zbytes, stream);
    k_deg<<<12500, 256, 0, stream>>>(dstp, deg);
    k_dinv<<<391, 256, 0, stream>>>(deg, dinv);
    k_scanA<<<98, 256, 0, stream>>>(deg, bsum);
    k_scanB<<<1, 64, 0, stream>>>(bsum);
    k_scanC<<<98, 256, 0, stream>>>(deg, bsum, offs);
    k_fill<<<12500, 256, 0, stream>>>(srcp, dstp, offs, cur, perm);
    k_gemm<0><<<1563, 256, 0, stream>>>(x, W1, bufA, N_NODES);
    k_spmm_bn_relu<<<25000, 256, 0, stream>>>(bufA, perm, offs, deg, dinv, b1, gamma, beta, rmean, rvar, bufB);
    k_gemm<1><<<1563, 256, 0, stream>>>(bufB, W2, bufA, N_NODES);
    k_spmm_pool<<<25000, 256, 0, stream>>>(bufA, perm, offs, deg, dinv, b2, batch, psum, pcnt);
    k_head<<<1, 128, 0, stream>>>(psum, pcnt, fw1, fb1, cw, cb, (float*)d_out);
}

// Round 3
// 823.501 us; speedup vs baseline: 1.6661x; 1.1195x over previous
//
#include <hip/hip_runtime.h>
#include <hip/hip_bf16.h>

#define N_NODES 100000
#define N_EDGES 3200000
#define CH 128
#define NG 128
#define BN_EPS 1e-5f
#define NBUCK 1024   // bucket = dst >> 7 (128 nodes per bucket)

__device__ __forceinline__ float bflo(unsigned int u) { return __uint_as_float(u << 16); }
__device__ __forceinline__ float bfhi(unsigned int u) { return __uint_as_float(u & 0xffff0000u); }
__device__ __forceinline__ unsigned int f2bf(float f) {  // RNE
    unsigned int u = __float_as_uint(f);
    return (u + 0x7fffu + ((u >> 16) & 1u)) >> 16;
}
__device__ __forceinline__ unsigned int pack2bf(float x, float y) {
    return f2bf(x) | (f2bf(y) << 16);
}

// ---------------- degree histogram + bucket histogram ----------------
__global__ __launch_bounds__(256) void k_deg(const int* __restrict__ dst, int* __restrict__ deg,
                                             int* __restrict__ bcnt) {
    __shared__ int lh[NBUCK];
    for (int i = threadIdx.x; i < NBUCK; i += 256) lh[i] = 0;
    __syncthreads();
    for (int e = blockIdx.x * 256 + threadIdx.x; e < N_EDGES; e += gridDim.x * 256) {
        int d = dst[e];
        atomicAdd(&deg[d], 1);
        atomicAdd(&lh[d >> 7], 1);
    }
    __syncthreads();
    for (int i = threadIdx.x; i < NBUCK; i += 256) {
        int v = lh[i];
        if (v) atomicAdd(&bcnt[i], v);
    }
}

__global__ __launch_bounds__(256) void k_dinv(const int* __restrict__ deg, float* __restrict__ dinv) {
    int i = blockIdx.x * 256 + threadIdx.x;
    if (i < N_NODES) dinv[i] = rsqrtf((float)(deg[i] + 1));  // +1 self loop
}

// ---------------- exclusive scan of deg -> offs ----------------
__global__ __launch_bounds__(256) void k_scanA(const int* __restrict__ deg, int* __restrict__ bsum) {
    __shared__ int sm[256];
    int base = blockIdx.x * 1024;
    int t = threadIdx.x;
    int idx = base + t * 4;
    int s = 0;
    if (idx < N_NODES) {
        int4 v = *(const int4*)&deg[idx];
        s = v.x + v.y + v.z + v.w;
    }
    sm[t] = s;
    __syncthreads();
    for (int off = 128; off > 0; off >>= 1) {
        if (t < off) sm[t] += sm[t + off];
        __syncthreads();
    }
    if (t == 0) bsum[blockIdx.x] = sm[0];
}

__global__ void k_scanB(int* __restrict__ bsum) {
    if (threadIdx.x == 0) {
        int run = 0;
        for (int b = 0; b < 98; ++b) { int v = bsum[b]; bsum[b] = run; run += v; }
    }
}

__global__ __launch_bounds__(256) void k_scanC(const int* __restrict__ deg, const int* __restrict__ bsum,
                                               int* __restrict__ offs) {
    __shared__ int sm[256];
    int base = blockIdx.x * 1024;
    int t = threadIdx.x;
    int idx = base + t * 4;
    int4 v = make_int4(0, 0, 0, 0);
    if (idx < N_NODES) v = *(const int4*)&deg[idx];
    int tsum = v.x + v.y + v.z + v.w;
    sm[t] = tsum;
    __syncthreads();
    for (int off = 1; off < 256; off <<= 1) {
        int val = sm[t];
        int add = (t >= off) ? sm[t - off] : 0;
        __syncthreads();
        sm[t] = val + add;
        __syncthreads();
    }
    int excl = sm[t] - tsum + bsum[blockIdx.x];
    if (idx + 0 < N_NODES) offs[idx + 0] = excl;
    if (idx + 1 < N_NODES) offs[idx + 1] = excl + v.x;
    if (idx + 2 < N_NODES) offs[idx + 2] = excl + v.x + v.y;
    if (idx + 3 < N_NODES) offs[idx + 3] = excl + v.x + v.y + v.z;
}

// ---------------- bucket scan: bcnt[1024] -> boffs, bcur ----------------
__global__ __launch_bounds__(256) void k_bscan(const int* __restrict__ bcnt, int* __restrict__ boffs,
                                               int* __restrict__ bcur) {
    __shared__ int sm[256];
    int t = threadIdx.x;
    int4 v = *(const int4*)&bcnt[t * 4];
    int tsum = v.x + v.y + v.z + v.w;
    sm[t] = tsum;
    __syncthreads();
    for (int off = 1; off < 256; off <<= 1) {
        int val = sm[t];
        int add = (t >= off) ? sm[t - off] : 0;
        __syncthreads();
        sm[t] = val + add;
        __syncthreads();
    }
    int excl = sm[t] - tsum;
    int o0 = excl, o1 = excl + v.x, o2 = o1 + v.y, o3 = o2 + v.z;
    boffs[t * 4] = o0; boffs[t * 4 + 1] = o1; boffs[t * 4 + 2] = o2; boffs[t * 4 + 3] = o3;
    bcur[t * 4] = o0;  bcur[t * 4 + 1] = o1;  bcur[t * 4 + 2] = o2;  bcur[t * 4 + 3] = o3;
}

// ---------------- pass C: bin edges into per-bucket pair segments ----------------
__global__ __launch_bounds__(256) void k_bin(const int* __restrict__ src, const int* __restrict__ dst,
                                             int* __restrict__ bcur, uint2* __restrict__ pairs) {
    __shared__ int lhist[NBUCK];
    __shared__ int lbase[NBUCK];
    int t = threadIdx.x;
    for (int i = t; i < NBUCK; i += 256) lhist[i] = 0;
    __syncthreads();
    int base = blockIdx.x * 4096;
    int dval[16], rank[16];
    #pragma unroll
    for (int i = 0; i < 16; ++i) {
        int e = base + t + i * 256;
        if (e < N_EDGES) {
            int d = dst[e];
            dval[i] = d;
            rank[i] = atomicAdd(&lhist[d >> 7], 1);
        } else dval[i] = -1;
    }
    __syncthreads();
    for (int i = t; i < NBUCK; i += 256) {
        int h = lhist[i];
        lbase[i] = h ? atomicAdd(&bcur[i], h) : 0;
    }
    __syncthreads();
    #pragma unroll
    for (int i = 0; i < 16; ++i) {
        int e = base + t + i * 256;
        if (dval[i] >= 0) {
            int b = dval[i] >> 7;
            uint2 pr;
            pr.x = (unsigned int)src[e];
            pr.y = (unsigned int)dval[i];
            pairs[lbase[b] + rank[i]] = pr;
        }
    }
}

// ---------------- pass D: per-bucket CSR fill (contiguous perm region per block) ----------------
__global__ __launch_bounds__(256) void k_bfill(const uint2* __restrict__ pairs, const int* __restrict__ boffs,
                                               const int* __restrict__ offs, int* __restrict__ perm) {
    __shared__ int lcur[128];
    int b = blockIdx.x;
    if (threadIdx.x < 128) lcur[threadIdx.x] = 0;
    __syncthreads();
    int p0 = boffs[b];
    int p1 = (b == NBUCK - 1) ? N_EDGES : boffs[b + 1];
    int d0 = b << 7;
    for (int p = p0 + threadIdx.x; p < p1; p += 256) {
        uint2 e = pairs[p];
        int d = (int)e.y;
        int r = atomicAdd(&lcur[d - d0], 1);
        perm[offs[d] + r] = (int)e.x;
    }
}

// ---------------- GEMM: Y_bf16[nrows,128] = X[nrows,128] @ W[128,128] ----------------
template <int BF16IN>
__global__ __launch_bounds__(256) void k_gemm(const void* __restrict__ Xv, const float* __restrict__ W,
                                              unsigned int* __restrict__ Yb, int nrows) {
    __shared__ float xsT[128 * 64];  // [k][r]
    int row0 = blockIdx.x * 64;
    int t = threadIdx.x;
    {
        int r = t >> 2, q = t & 3;
        int grow = row0 + r;
        bool ok = grow < nrows;
        if (BF16IN) {
            const uint2* srcp = (const uint2*)((const unsigned int*)Xv + (size_t)grow * 64 + q * 16);
            #pragma unroll
            for (int i = 0; i < 8; ++i) {
                uint2 u = ok ? srcp[i] : make_uint2(0, 0);
                int c = q * 32 + i * 4;
                xsT[(c + 0) * 64 + r] = bflo(u.x);
                xsT[(c + 1) * 64 + r] = bfhi(u.x);
                xsT[(c + 2) * 64 + r] = bflo(u.y);
                xsT[(c + 3) * 64 + r] = bfhi(u.y);
            }
        } else {
            const float4* srcp = (const float4*)((const float*)Xv + (size_t)grow * CH + q * 32);
            #pragma unroll
            for (int i = 0; i < 8; ++i) {
                float4 v = ok ? srcp[i] : make_float4(0.f, 0.f, 0.f, 0.f);
                int c = q * 32 + i * 4;
                xsT[(c + 0) * 64 + r] = v.x;
                xsT[(c + 1) * 64 + r] = v.y;
                xsT[(c + 2) * 64 + r] = v.z;
                xsT[(c + 3) * 64 + r] = v.w;
            }
        }
    }
    __syncthreads();
    int tx = t & 15, ty = t >> 4;
    float acc[4][8];
    #pragma unroll
    for (int i = 0; i < 4; ++i)
        #pragma unroll
        for (int j = 0; j < 8; ++j) acc[i][j] = 0.f;

    const float4* xs4 = (const float4*)xsT;
    #pragma unroll 4
    for (int k = 0; k < 128; ++k) {
        float4 a = xs4[k * 16 + ty];
        float4 w0 = *(const float4*)&W[k * CH + tx * 8];
        float4 w1 = *(const float4*)&W[k * CH + tx * 8 + 4];
        float av[4] = {a.x, a.y, a.z, a.w};
        float wv[8] = {w0.x, w0.y, w0.z, w0.w, w1.x, w1.y, w1.z, w1.w};
        #pragma unroll
        for (int i = 0; i < 4; ++i)
            #pragma unroll
            for (int j = 0; j < 8; ++j) acc[i][j] += av[i] * wv[j];
    }
    #pragma unroll
    for (int i = 0; i < 4; ++i) {
        int grow = row0 + ty * 4 + i;
        if (grow < nrows) {
            unsigned int o[4];
            #pragma unroll
            for (int j = 0; j < 4; ++j) o[j] = pack2bf(acc[i][2 * j], acc[i][2 * j + 1]);
            *(uint4*)&Yb[(size_t)grow * 64 + tx * 4] = *(uint4*)o;
        }
    }
}

// ---------------- SpMM gather core: 4 edge-slots x 16 lanes, uint4 (8ch) per lane ----------------
#define SPMM_GATHER()                                                                  \
    int w = threadIdx.x >> 6;                                                          \
    int row = __builtin_amdgcn_readfirstlane(blockIdx.x * 4 + w);                      \
    int lane = threadIdx.x & 63;                                                       \
    int g = lane >> 4, c = lane & 15;                                                  \
    float di = dinv[row];                                                              \
    float acc[8];                                                                      \
    _Pragma("unroll") for (int i = 0; i < 8; ++i) acc[i] = 0.f;                        \
    int beg = offs[row], end = beg + deg[row];                                         \
    int j = beg + g;                                                                   \
    for (; j + 4 < end; j += 8) {                                                      \
        int s0 = perm[j], s1 = perm[j + 4];                                            \
        float f0 = dinv[s0], f1 = dinv[s1];                                            \
        uint4 v0 = xw4[(size_t)s0 * 16 + c];                                           \
        uint4 v1 = xw4[(size_t)s1 * 16 + c];                                           \
        f0 *= di; f1 *= di;                                                            \
        acc[0] += f0 * bflo(v0.x) + f1 * bflo(v1.x);                                   \
        acc[1] += f0 * bfhi(v0.x) + f1 * bfhi(v1.x);                                   \
        acc[2] += f0 * bflo(v0.y) + f1 * bflo(v1.y);                                   \
        acc[3] += f0 * bfhi(v0.y) + f1 * bfhi(v1.y);                                   \
        acc[4] += f0 * bflo(v0.z) + f1 * bflo(v1.z);                                   \
        acc[5] += f0 * bfhi(v0.z) + f1 * bfhi(v1.z);                                   \
        acc[6] += f0 * bflo(v0.w) + f1 * bflo(v1.w);                                   \
        acc[7] += f0 * bfhi(v0.w) + f1 * bfhi(v1.w);                                   \
    }                                                                                  \
    if (j < end) {                                                                     \
        int s = perm[j];                                                               \
        float f = di * dinv[s];                                                        \
        uint4 v = xw4[(size_t)s * 16 + c];                                             \
        acc[0] += f * bflo(v.x); acc[1] += f * bfhi(v.x);                              \
        acc[2] += f * bflo(v.y); acc[3] += f * bfhi(v.y);                              \
        acc[4] += f * bflo(v.z); acc[5] += f * bfhi(v.z);                              \
        acc[6] += f * bflo(v.w); acc[7] += f * bfhi(v.w);                              \
    }                                                                                  \
    _Pragma("unroll") for (int i = 0; i < 8; ++i) {                                    \
        acc[i] += __shfl_xor(acc[i], 16, 64);                                          \
        acc[i] += __shfl_xor(acc[i], 32, 64);                                          \
    }

// ---------------- SpMM layer 1: aggregate + bias + BN + ReLU -> bf16 ----------------
__global__ __launch_bounds__(256) void k_spmm_bn_relu(
    const uint4* __restrict__ xw4, const int* __restrict__ perm, const int* __restrict__ offs,
    const int* __restrict__ deg, const float* __restrict__ dinv, const float* __restrict__ bias,
    const float* __restrict__ gamma, const float* __restrict__ beta,
    const float* __restrict__ rmean, const float* __restrict__ rvar, uint4* __restrict__ outb) {
    SPMM_GATHER()
    if (g == 0) {
        uint4 v = xw4[(size_t)row * 16 + c];
        float sd = di * di;
        acc[0] += sd * bflo(v.x); acc[1] += sd * bfhi(v.x);
        acc[2] += sd * bflo(v.y); acc[3] += sd * bfhi(v.y);
        acc[4] += sd * bflo(v.z); acc[5] += sd * bfhi(v.z);
        acc[6] += sd * bflo(v.w); acc[7] += sd * bfhi(v.w);
        int ch = c * 8;
        float r[8];
        #pragma unroll
        for (int i = 0; i < 8; ++i) {
            float sc = gamma[ch + i] * rsqrtf(rvar[ch + i] + BN_EPS);
            r[i] = fmaxf((acc[i] + bias[ch + i] - rmean[ch + i]) * sc + beta[ch + i], 0.f);
        }
        uint4 o;
        o.x = pack2bf(r[0], r[1]); o.y = pack2bf(r[2], r[3]);
        o.z = pack2bf(r[4], r[5]); o.w = pack2bf(r[6], r[7]);
        outb[(size_t)row * 16 + c] = o;
    }
}

// ---------------- SpMM layer 2: aggregate + bias + pooled-sum (block-reduced atomics) ----------------
__global__ __launch_bounds__(256) void k_spmm_pool(
    const uint4* __restrict__ xw4, const int* __restrict__ perm, const int* __restrict__ offs,
    const int* __restrict__ deg, const float* __restrict__ dinv, const float* __restrict__ bias,
    const int* __restrict__ batch, float* __restrict__ psum, int* __restrict__ pcnt) {
    __shared__ float red[4][128];
    __shared__ int gid[4];
    SPMM_GATHER()
    if (g == 0) {
        uint4 v = xw4[(size_t)row * 16 + c];
        float sd = di * di;
        acc[0] += sd * bflo(v.x); acc[1] += sd * bfhi(v.x);
        acc[2] += sd * bflo(v.y); acc[3] += sd * bfhi(v.y);
        acc[4] += sd * bflo(v.z); acc[5] += sd * bfhi(v.z);
        acc[6] += sd * bflo(v.w); acc[7] += sd * bfhi(v.w);
        int ch = c * 8;
        #pragma unroll
        for (int i = 0; i < 8; ++i) red[w][ch + i] = acc[i] + bias[ch + i];
    }
    if (lane == 0) gid[w] = batch[row];
    __syncthreads();
    bool same = (gid[0] == gid[1]) && (gid[1] == gid[2]) && (gid[2] == gid[3]);
    int c0 = lane * 2;
    if (same) {
        if (w == 0) {
            float sx = red[0][c0] + red[1][c0] + red[2][c0] + red[3][c0];
            float sy = red[0][c0 + 1] + red[1][c0 + 1] + red[2][c0 + 1] + red[3][c0 + 1];
            unsafeAtomicAdd(&psum[gid[0] * CH + c0], sx);
            unsafeAtomicAdd(&psum[gid[0] * CH + c0 + 1], sy);
            if (lane == 0) atomicAdd(&pcnt[gid[0]], 4);
        }
    } else {
        unsafeAtomicAdd(&psum[gid[w] * CH + c0], red[w][c0]);
        unsafeAtomicAdd(&psum[gid[w] * CH + c0 + 1], red[w][c0 + 1]);
        if (lane == 0) atomicAdd(&pcnt[gid[w]], 1);
    }
}

// ---------------- head: pooled mean -> FC(relu) -> classifier ----------------
__global__ __launch_bounds__(128) void k_head(const float* __restrict__ psum, const int* __restrict__ pcnt,
                                              const float* __restrict__ fw1, const float* __restrict__ fb1,
                                              const float* __restrict__ cw, const float* __restrict__ cb,
                                              float* __restrict__ out) {
    __shared__ float fws[128 * 64];
    for (int i = threadIdx.x; i < 128 * 64; i += 128) fws[i] = fw1[i];
    __syncthreads();
    int g = threadIdx.x;
    float z[64];
    #pragma unroll
    for (int j = 0; j < 64; ++j) z[j] = fb1[j];
    float cnt = fmaxf((float)pcnt[g], 1.f);
    float inv = 1.f / cnt;
    for (int c = 0; c < 128; ++c) {
        float p = psum[g * CH + c] * inv;
        #pragma unroll
        for (int j = 0; j < 64; ++j) z[j] += p * fws[c * 64 + j];
    }
    float o0 = cb[0], o1 = cb[1];
    #pragma unroll
    for (int j = 0; j < 64; ++j) {
        float zz = fmaxf(z[j], 0.f);
        o0 += zz * cw[j * 2];
        o1 += zz * cw[j * 2 + 1];
    }
    out[g * 2] = o0;
    out[g * 2 + 1] = o1;
}

extern "C" void kernel_launch(void* const* d_in, const int* in_sizes, int n_in,
                              void* d_out, int out_size, void* d_ws, size_t ws_size,
                              hipStream_t stream) {
    const float* x     = (const float*)d_in[0];
    const int*   ei    = (const int*)d_in[1];
    const int*   batch = (const int*)d_in[2];
    const float* W1    = (const float*)d_in[3];
    const float* b1    = (const float*)d_in[4];
    const float* gamma = (const float*)d_in[5];
    const float* beta  = (const float*)d_in[6];
    const float* rmean = (const float*)d_in[7];
    const float* rvar  = (const float*)d_in[8];
    const float* W2    = (const float*)d_in[9];
    const float* b2    = (const float*)d_in[10];
    const float* fw1   = (const float*)d_in[11];
    const float* fb1   = (const float*)d_in[12];
    const float* cw    = (const float*)d_in[13];
    const float* cb    = (const float*)d_in[14];
    const int* srcp = ei;
    const int* dstp = ei + N_EDGES;

    char* w = (char*)d_ws;
    int*   deg   = (int*)w;   w += 400000;
    float* psum  = (float*)w; w += 65536;
    int*   pcnt  = (int*)w;   w += 512;
    int*   bcnt  = (int*)w;   w += 4096;
    size_t zbytes = 400000 + 65536 + 512 + 4096;
    int*   offs  = (int*)w;   w += 400000;
    float* dinv  = (float*)w; w += 400000;
    int*   bsum  = (int*)w;   w += 4096;
    int*   boffs = (int*)w;   w += 4096;
    int*   bcur  = (int*)w;   w += 4096;
    uint2* pairs = (uint2*)w; w += 25600000;
    int*   perm  = (int*)w;   w += 12800000;
    unsigned int* bufA = (unsigned int*)w; w += 25600000;  // bf16x2 [100k,64]
    unsigned int* bufB = (unsigned int*)w; w += 25600000;  // bf16x2 [100k,64]

    hipMemsetAsync(d_ws, 0, zbytes, stream);
    k_deg<<<200, 256, 0, stream>>>(dstp, deg, bcnt);
    k_dinv<<<391, 256, 0, stream>>>(deg, dinv);
    k_scanA<<<98, 256, 0, stream>>>(deg, bsum);
    k_scanB<<<1, 64, 0, stream>>>(bsum);
    k_scanC<<<98, 256, 0, stream>>>(deg, bsum, offs);
    k_bscan<<<1, 256, 0, stream>>>(bcnt, boffs, bcur);
    k_bin<<<782, 256, 0, stream>>>(srcp, dstp, bcur, pairs);
    k_bfill<<<NBUCK, 256, 0, stream>>>(pairs, boffs, offs, perm);
    k_gemm<0><<<1563, 256, 0, stream>>>(x, W1, bufA, N_NODES);
    k_spmm_bn_relu<<<25000, 256, 0, stream>>>((const uint4*)bufA, perm, offs, deg, dinv, b1, gamma, beta, rmean, rvar, (uint4*)bufB);
    k_gemm<1><<<1563, 256, 0, stream>>>(bufB, W2, bufA, N_NODES);
    k_spmm_pool<<<25000, 256, 0, stream>>>((const uint4*)bufA, perm, offs, deg, dinv, b2, batch, psum, pcnt);
    k_head<<<1, 128, 0, stream>>>(psum, pcnt, fw1, fb1, cw, cb, (float*)d_out);
}

// Round 4
// 792.172 us; speedup vs baseline: 1.7320x; 1.0395x over previous
//
#include <hip/hip_runtime.h>
#include <hip/hip_bf16.h>

#define N_NODES 100000
#define N_EDGES 3200000
#define CH 128
#define NG 128
#define BN_EPS 1e-5f
#define NBUCK 1024   // bucket = dst >> 7 (128 nodes per bucket)

__device__ __forceinline__ float bflo(unsigned int u) { return __uint_as_float(u << 16); }
__device__ __forceinline__ float bfhi(unsigned int u) { return __uint_as_float(u & 0xffff0000u); }
__device__ __forceinline__ unsigned int f2bf(float f) {  // RNE
    unsigned int u = __float_as_uint(f);
    return (u + 0x7fffu + ((u >> 16) & 1u)) >> 16;
}
__device__ __forceinline__ unsigned int pack2bf(float x, float y) {
    return f2bf(x) | (f2bf(y) << 16);
}

// ---------------- bucket histogram only (deg fused into k_bin) ----------------
__global__ __launch_bounds__(256) void k_bhist(const int* __restrict__ dst, int* __restrict__ bcnt) {
    __shared__ int lh[NBUCK];
    for (int i = threadIdx.x; i < NBUCK; i += 256) lh[i] = 0;
    __syncthreads();
    for (int e = blockIdx.x * 256 + threadIdx.x; e < N_EDGES; e += gridDim.x * 256)
        atomicAdd(&lh[dst[e] >> 7], 1);
    __syncthreads();
    for (int i = threadIdx.x; i < NBUCK; i += 256) {
        int v = lh[i];
        if (v) atomicAdd(&bcnt[i], v);
    }
}

__global__ __launch_bounds__(256) void k_dinv(const int* __restrict__ deg, float* __restrict__ dinv) {
    int i = blockIdx.x * 256 + threadIdx.x;
    if (i < N_NODES) dinv[i] = rsqrtf((float)(deg[i] + 1));  // +1 self loop
}

// ---------------- exclusive scan of deg -> offs ----------------
__global__ __launch_bounds__(256) void k_scanA(const int* __restrict__ deg, int* __restrict__ bsum) {
    __shared__ int sm[256];
    int base = blockIdx.x * 1024;
    int t = threadIdx.x;
    int idx = base + t * 4;
    int s = 0;
    if (idx < N_NODES) {
        int4 v = *(const int4*)&deg[idx];
        s = v.x + v.y + v.z + v.w;
    }
    sm[t] = s;
    __syncthreads();
    for (int off = 128; off > 0; off >>= 1) {
        if (t < off) sm[t] += sm[t + off];
        __syncthreads();
    }
    if (t == 0) bsum[blockIdx.x] = sm[0];
}

__global__ void k_scanB(int* __restrict__ bsum) {
    if (threadIdx.x == 0) {
        int run = 0;
        for (int b = 0; b < 98; ++b) { int v = bsum[b]; bsum[b] = run; run += v; }
    }
}

__global__ __launch_bounds__(256) void k_scanC(const int* __restrict__ deg, const int* __restrict__ bsum,
                                               int* __restrict__ offs) {
    __shared__ int sm[256];
    int base = blockIdx.x * 1024;
    int t = threadIdx.x;
    int idx = base + t * 4;
    int4 v = make_int4(0, 0, 0, 0);
    if (idx < N_NODES) v = *(const int4*)&deg[idx];
    int tsum = v.x + v.y + v.z + v.w;
    sm[t] = tsum;
    __syncthreads();
    for (int off = 1; off < 256; off <<= 1) {
        int val = sm[t];
        int add = (t >= off) ? sm[t - off] : 0;
        __syncthreads();
        sm[t] = val + add;
        __syncthreads();
    }
    int excl = sm[t] - tsum + bsum[blockIdx.x];
    if (idx + 0 < N_NODES) offs[idx + 0] = excl;
    if (idx + 1 < N_NODES) offs[idx + 1] = excl + v.x;
    if (idx + 2 < N_NODES) offs[idx + 2] = excl + v.x + v.y;
    if (idx + 3 < N_NODES) offs[idx + 3] = excl + v.x + v.y + v.z;
}

// ---------------- bucket scan: bcnt[1024] -> boffs, bcur ----------------
__global__ __launch_bounds__(256) void k_bscan(const int* __restrict__ bcnt, int* __restrict__ boffs,
                                               int* __restrict__ bcur) {
    __shared__ int sm[256];
    int t = threadIdx.x;
    int4 v = *(const int4*)&bcnt[t * 4];
    int tsum = v.x + v.y + v.z + v.w;
    sm[t] = tsum;
    __syncthreads();
    for (int off = 1; off < 256; off <<= 1) {
        int val = sm[t];
        int add = (t >= off) ? sm[t - off] : 0;
        __syncthreads();
        sm[t] = val + add;
        __syncthreads();
    }
    int excl = sm[t] - tsum;
    int o0 = excl, o1 = excl + v.x, o2 = o1 + v.y, o3 = o2 + v.z;
    boffs[t * 4] = o0; boffs[t * 4 + 1] = o1; boffs[t * 4 + 2] = o2; boffs[t * 4 + 3] = o3;
    bcur[t * 4] = o0;  bcur[t * 4 + 1] = o1;  bcur[t * 4 + 2] = o2;  bcur[t * 4 + 3] = o3;
}

// ---------------- pass C: bin edges into per-bucket packed segments + deg histogram ----------------
// packed entry: (src << 7) | (dst & 127)   [src < 2^17]
__global__ __launch_bounds__(256) void k_bin(const int* __restrict__ src, const int* __restrict__ dst,
                                             int* __restrict__ bcur, int* __restrict__ deg,
                                             unsigned int* __restrict__ pairs) {
    __shared__ int lhist[NBUCK];
    __shared__ int lbase[NBUCK];
    int t = threadIdx.x;
    for (int i = t; i < NBUCK; i += 256) lhist[i] = 0;
    __syncthreads();
    int base = blockIdx.x * 4096;
    int dval[16], rank[16];
    #pragma unroll
    for (int i = 0; i < 16; ++i) {
        int e = base + t + i * 256;
        if (e < N_EDGES) {
            int d = dst[e];
            dval[i] = d;
            rank[i] = atomicAdd(&lhist[d >> 7], 1);
            atomicAdd(&deg[d], 1);
        } else dval[i] = -1;
    }
    __syncthreads();
    for (int i = t; i < NBUCK; i += 256) {
        int h = lhist[i];
        lbase[i] = h ? atomicAdd(&bcur[i], h) : 0;
    }
    __syncthreads();
    #pragma unroll
    for (int i = 0; i < 16; ++i) {
        int e = base + t + i * 256;
        if (dval[i] >= 0) {
            int b = dval[i] >> 7;
            unsigned int p = ((unsigned int)src[e] << 7) | ((unsigned int)dval[i] & 127u);
            pairs[lbase[b] + rank[i]] = p;
        }
    }
}

// ---------------- pass D: per-bucket CSR fill (contiguous perm region per block) ----------------
__global__ __launch_bounds__(256) void k_bfill(const unsigned int* __restrict__ pairs,
                                               const int* __restrict__ boffs,
                                               const int* __restrict__ offs, int* __restrict__ perm) {
    __shared__ int lcur[128];
    int b = blockIdx.x;
    if (threadIdx.x < 128) lcur[threadIdx.x] = 0;
    __syncthreads();
    int p0 = boffs[b];
    int p1 = (b == NBUCK - 1) ? N_EDGES : boffs[b + 1];
    int d0 = b << 7;
    for (int p = p0 + threadIdx.x; p < p1; p += 256) {
        unsigned int e = pairs[p];
        int local = (int)(e & 127u);
        int r = atomicAdd(&lcur[local], 1);
        perm[offs[d0 + local] + r] = (int)(e >> 7);
    }
}

// ---------------- GEMM: Y_bf16[nrows,128] = X[nrows,128] @ W[128,128] ----------------
template <int BF16IN>
__global__ __launch_bounds__(256) void k_gemm(const void* __restrict__ Xv, const float* __restrict__ W,
                                              unsigned int* __restrict__ Yb, int nrows) {
    __shared__ float xsT[128 * 64];  // [k][r]
    int row0 = blockIdx.x * 64;
    int t = threadIdx.x;
    {
        int r = t >> 2, q = t & 3;
        int grow = row0 + r;
        bool ok = grow < nrows;
        if (BF16IN) {
            const uint2* srcp = (const uint2*)((const unsigned int*)Xv + (size_t)grow * 64 + q * 16);
            #pragma unroll
            for (int i = 0; i < 8; ++i) {
                uint2 u = ok ? srcp[i] : make_uint2(0, 0);
                int c = q * 32 + i * 4;
                xsT[(c + 0) * 64 + r] = bflo(u.x);
                xsT[(c + 1) * 64 + r] = bfhi(u.x);
                xsT[(c + 2) * 64 + r] = bflo(u.y);
                xsT[(c + 3) * 64 + r] = bfhi(u.y);
            }
        } else {
            const float4* srcp = (const float4*)((const float*)Xv + (size_t)grow * CH + q * 32);
            #pragma unroll
            for (int i = 0; i < 8; ++i) {
                float4 v = ok ? srcp[i] : make_float4(0.f, 0.f, 0.f, 0.f);
                int c = q * 32 + i * 4;
                xsT[(c + 0) * 64 + r] = v.x;
                xsT[(c + 1) * 64 + r] = v.y;
                xsT[(c + 2) * 64 + r] = v.z;
                xsT[(c + 3) * 64 + r] = v.w;
            }
        }
    }
    __syncthreads();
    int tx = t & 15, ty = t >> 4;
    float acc[4][8];
    #pragma unroll
    for (int i = 0; i < 4; ++i)
        #pragma unroll
        for (int j = 0; j < 8; ++j) acc[i][j] = 0.f;

    const float4* xs4 = (const float4*)xsT;
    #pragma unroll 4
    for (int k = 0; k < 128; ++k) {
        float4 a = xs4[k * 16 + ty];
        float4 w0 = *(const float4*)&W[k * CH + tx * 8];
        float4 w1 = *(const float4*)&W[k * CH + tx * 8 + 4];
        float av[4] = {a.x, a.y, a.z, a.w};
        float wv[8] = {w0.x, w0.y, w0.z, w0.w, w1.x, w1.y, w1.z, w1.w};
        #pragma unroll
        for (int i = 0; i < 4; ++i)
            #pragma unroll
            for (int j = 0; j < 8; ++j) acc[i][j] += av[i] * wv[j];
    }
    #pragma unroll
    for (int i = 0; i < 4; ++i) {
        int grow = row0 + ty * 4 + i;
        if (grow < nrows) {
            unsigned int o[4];
            #pragma unroll
            for (int j = 0; j < 4; ++j) o[j] = pack2bf(acc[i][2 * j], acc[i][2 * j + 1]);
            *(uint4*)&Yb[(size_t)grow * 64 + tx * 4] = *(uint4*)o;
        }
    }
}

// ---------------- SpMM gather core: 4 edge-slots x 16 lanes, 4x unrolled uint4 loads ----------------
#define ACC8(f, v)                                                                     \
    acc[0] += f * bflo(v.x); acc[1] += f * bfhi(v.x);                                  \
    acc[2] += f * bflo(v.y); acc[3] += f * bfhi(v.y);                                  \
    acc[4] += f * bflo(v.z); acc[5] += f * bfhi(v.z);                                  \
    acc[6] += f * bflo(v.w); acc[7] += f * bfhi(v.w);

#define SPMM_GATHER()                                                                  \
    int w = threadIdx.x >> 6;                                                          \
    int row = __builtin_amdgcn_readfirstlane(blockIdx.x * 4 + w);                      \
    int lane = threadIdx.x & 63;                                                       \
    int g = lane >> 4, c = lane & 15;                                                  \
    float di = dinv[row];                                                              \
    float acc[8];                                                                      \
    _Pragma("unroll") for (int i = 0; i < 8; ++i) acc[i] = 0.f;                        \
    int beg = offs[row], end = beg + deg[row];                                         \
    int j = beg + g;                                                                   \
    for (; j + 12 < end; j += 16) {                                                    \
        int s0 = perm[j], s1 = perm[j + 4], s2 = perm[j + 8], s3 = perm[j + 12];       \
        float f0 = dinv[s0], f1 = dinv[s1], f2 = dinv[s2], f3 = dinv[s3];              \
        uint4 v0 = xw4[(size_t)s0 * 16 + c];                                           \
        uint4 v1 = xw4[(size_t)s1 * 16 + c];                                           \
        uint4 v2 = xw4[(size_t)s2 * 16 + c];                                           \
        uint4 v3 = xw4[(size_t)s3 * 16 + c];                                           \
        f0 *= di; f1 *= di; f2 *= di; f3 *= di;                                        \
        ACC8(f0, v0) ACC8(f1, v1) ACC8(f2, v2) ACC8(f3, v3)                            \
    }                                                                                  \
    for (; j + 4 < end; j += 8) {                                                      \
        int s0 = perm[j], s1 = perm[j + 4];                                            \
        float f0 = di * dinv[s0], f1 = di * dinv[s1];                                  \
        uint4 v0 = xw4[(size_t)s0 * 16 + c];                                           \
        uint4 v1 = xw4[(size_t)s1 * 16 + c];                                           \
        ACC8(f0, v0) ACC8(f1, v1)                                                      \
    }                                                                                  \
    if (j < end) {                                                                     \
        int s = perm[j];                                                               \
        float f = di * dinv[s];                                                        \
        uint4 v = xw4[(size_t)s * 16 + c];                                             \
        ACC8(f, v)                                                                     \
    }                                                                                  \
    _Pragma("unroll") for (int i = 0; i < 8; ++i) {                                    \
        acc[i] += __shfl_xor(acc[i], 16, 64);                                          \
        acc[i] += __shfl_xor(acc[i], 32, 64);                                          \
    }

// ---------------- SpMM layer 1: aggregate + bias + BN + ReLU -> bf16 ----------------
__global__ __launch_bounds__(256) void k_spmm_bn_relu(
    const uint4* __restrict__ xw4, const int* __restrict__ perm, const int* __restrict__ offs,
    const int* __restrict__ deg, const float* __restrict__ dinv, const float* __restrict__ bias,
    const float* __restrict__ gamma, const float* __restrict__ beta,
    const float* __restrict__ rmean, const float* __restrict__ rvar, uint4* __restrict__ outb) {
    SPMM_GATHER()
    if (g == 0) {
        uint4 v = xw4[(size_t)row * 16 + c];
        float sd = di * di;
        ACC8(sd, v)
        int ch = c * 8;
        float r[8];
        #pragma unroll
        for (int i = 0; i < 8; ++i) {
            float sc = gamma[ch + i] * rsqrtf(rvar[ch + i] + BN_EPS);
            r[i] = fmaxf((acc[i] + bias[ch + i] - rmean[ch + i]) * sc + beta[ch + i], 0.f);
        }
        uint4 o;
        o.x = pack2bf(r[0], r[1]); o.y = pack2bf(r[2], r[3]);
        o.z = pack2bf(r[4], r[5]); o.w = pack2bf(r[6], r[7]);
        outb[(size_t)row * 16 + c] = o;
    }
}

// ---------------- SpMM layer 2: aggregate + bias + pooled-sum (block-reduced atomics) ----------------
__global__ __launch_bounds__(256) void k_spmm_pool(
    const uint4* __restrict__ xw4, const int* __restrict__ perm, const int* __restrict__ offs,
    const int* __restrict__ deg, const float* __restrict__ dinv, const float* __restrict__ bias,
    const int* __restrict__ batch, float* __restrict__ psum, int* __restrict__ pcnt) {
    __shared__ float red[4][128];
    __shared__ int gid[4];
    SPMM_GATHER()
    if (g == 0) {
        uint4 v = xw4[(size_t)row * 16 + c];
        float sd = di * di;
        ACC8(sd, v)
        int ch = c * 8;
        #pragma unroll
        for (int i = 0; i < 8; ++i) red[w][ch + i] = acc[i] + bias[ch + i];
    }
    if (lane == 0) gid[w] = batch[row];
    __syncthreads();
    bool same = (gid[0] == gid[1]) && (gid[1] == gid[2]) && (gid[2] == gid[3]);
    int c0 = lane * 2;
    if (same) {
        if (w == 0) {
            float sx = red[0][c0] + red[1][c0] + red[2][c0] + red[3][c0];
            float sy = red[0][c0 + 1] + red[1][c0 + 1] + red[2][c0 + 1] + red[3][c0 + 1];
            unsafeAtomicAdd(&psum[gid[0] * CH + c0], sx);
            unsafeAtomicAdd(&psum[gid[0] * CH + c0 + 1], sy);
            if (lane == 0) atomicAdd(&pcnt[gid[0]], 4);
        }
    } else {
        unsafeAtomicAdd(&psum[gid[w] * CH + c0], red[w][c0]);
        unsafeAtomicAdd(&psum[gid[w] * CH + c0 + 1], red[w][c0 + 1]);
        if (lane == 0) atomicAdd(&pcnt[gid[w]], 1);
    }
}

// ---------------- head: pooled mean -> FC(relu) -> classifier ----------------
__global__ __launch_bounds__(128) void k_head(const float* __restrict__ psum, const int* __restrict__ pcnt,
                                              const float* __restrict__ fw1, const float* __restrict__ fb1,
                                              const float* __restrict__ cw, const float* __restrict__ cb,
                                              float* __restrict__ out) {
    __shared__ float fws[128 * 64];
    for (int i = threadIdx.x; i < 128 * 64; i += 128) fws[i] = fw1[i];
    __syncthreads();
    int g = threadIdx.x;
    float z[64];
    #pragma unroll
    for (int j = 0; j < 64; ++j) z[j] = fb1[j];
    float cnt = fmaxf((float)pcnt[g], 1.f);
    float inv = 1.f / cnt;
    for (int c = 0; c < 128; ++c) {
        float p = psum[g * CH + c] * inv;
        #pragma unroll
        for (int j = 0; j < 64; ++j) z[j] += p * fws[c * 64 + j];
    }
    float o0 = cb[0], o1 = cb[1];
    #pragma unroll
    for (int j = 0; j < 64; ++j) {
        float zz = fmaxf(z[j], 0.f);
        o0 += zz * cw[j * 2];
        o1 += zz * cw[j * 2 + 1];
    }
    out[g * 2] = o0;
    out[g * 2 + 1] = o1;
}

extern "C" void kernel_launch(void* const* d_in, const int* in_sizes, int n_in,
                              void* d_out, int out_size, void* d_ws, size_t ws_size,
                              hipStream_t stream) {
    const float* x     = (const float*)d_in[0];
    const int*   ei    = (const int*)d_in[1];
    const int*   batch = (const int*)d_in[2];
    const float* W1    = (const float*)d_in[3];
    const float* b1    = (const float*)d_in[4];
    const float* gamma = (const float*)d_in[5];
    const float* beta  = (const float*)d_in[6];
    const float* rmean = (const float*)d_in[7];
    const float* rvar  = (const float*)d_in[8];
    const float* W2    = (const float*)d_in[9];
    const float* b2    = (const float*)d_in[10];
    const float* fw1   = (const float*)d_in[11];
    const float* fb1   = (const float*)d_in[12];
    const float* cw    = (const float*)d_in[13];
    const float* cb    = (const float*)d_in[14];
    const int* srcp = ei;
    const int* dstp = ei + N_EDGES;

    char* w = (char*)d_ws;
    int*   deg   = (int*)w;   w += 400000;
    float* psum  = (float*)w; w += 65536;
    int*   pcnt  = (int*)w;   w += 512;
    int*   bcnt  = (int*)w;   w += 4096;
    size_t zbytes = 400000 + 65536 + 512 + 4096;
    int*   offs  = (int*)w;   w += 400000;
    float* dinv  = (float*)w; w += 400000;
    int*   bsum  = (int*)w;   w += 4096;
    int*   boffs = (int*)w;   w += 4096;
    int*   bcur  = (int*)w;   w += 4096;
    unsigned int* pairs = (unsigned int*)w; w += 12800000;
    int*   perm  = (int*)w;   w += 12800000;
    unsigned int* bufA = (unsigned int*)w; w += 25600000;  // bf16x2 [100k,64]
    unsigned int* bufB = (unsigned int*)w; w += 25600000;  // bf16x2 [100k,64]

    hipMemsetAsync(d_ws, 0, zbytes, stream);
    k_bhist<<<200, 256, 0, stream>>>(dstp, bcnt);
    k_bscan<<<1, 256, 0, stream>>>(bcnt, boffs, bcur);
    k_bin<<<782, 256, 0, stream>>>(srcp, dstp, bcur, deg, pairs);
    k_dinv<<<391, 256, 0, stream>>>(deg, dinv);
    k_scanA<<<98, 256, 0, stream>>>(deg, bsum);
    k_scanB<<<1, 64, 0, stream>>>(bsum);
    k_scanC<<<98, 256, 0, stream>>>(deg, bsum, offs);
    k_bfill<<<NBUCK, 256, 0, stream>>>(pairs, boffs, offs, perm);
    k_gemm<0><<<1563, 256, 0, stream>>>(x, W1, bufA, N_NODES);
    k_spmm_bn_relu<<<25000, 256, 0, stream>>>((const uint4*)bufA, perm, offs, deg, dinv, b1, gamma, beta, rmean, rvar, (uint4*)bufB);
    k_gemm<1><<<1563, 256, 0, stream>>>(bufB, W2, bufA, N_NODES);
    k_spmm_pool<<<25000, 256, 0, stream>>>((const uint4*)bufA, perm, offs, deg, dinv, b2, batch, psum, pcnt);
    k_head<<<1, 128, 0, stream>>>(psum, pcnt, fw1, fb1, cw, cb, (float*)d_out);
}

// Round 5
// 712.944 us; speedup vs baseline: 1.9245x; 1.1111x over previous
//
#include <hip/hip_runtime.h>
#include <hip/hip_bf16.h>

#define N_NODES 100000
#define N_EDGES 3200000
#define CH 128
#define NG 128
#define BN_EPS 1e-5f
#define NBUCK 1024   // bucket = dst >> 7 (128 nodes per bucket)
#define EPB 16384    // edges per k_bin block

__device__ __forceinline__ float bflo(unsigned int u) { return __uint_as_float(u << 16); }
__device__ __forceinline__ float bfhi(unsigned int u) { return __uint_as_float(u & 0xffff0000u); }
__device__ __forceinline__ unsigned int f2bf(float f) {  // RNE
    unsigned int u = __float_as_uint(f);
    return (u + 0x7fffu + ((u >> 16) & 1u)) >> 16;
}
__device__ __forceinline__ unsigned int pack2bf(float x, float y) {
    return f2bf(x) | (f2bf(y) << 16);
}

// ---------------- bucket histogram ----------------
__global__ __launch_bounds__(256) void k_bhist(const int* __restrict__ dst, int* __restrict__ bcnt) {
    __shared__ int lh[NBUCK];
    for (int i = threadIdx.x; i < NBUCK; i += 256) lh[i] = 0;
    __syncthreads();
    for (int e = blockIdx.x * 256 + threadIdx.x; e < N_EDGES; e += gridDim.x * 256)
        atomicAdd(&lh[dst[e] >> 7], 1);
    __syncthreads();
    for (int i = threadIdx.x; i < NBUCK; i += 256) {
        int v = lh[i];
        if (v) atomicAdd(&bcnt[i], v);
    }
}

// ---------------- bucket scan: bcnt[1024] -> boffs, bcur ----------------
__global__ __launch_bounds__(256) void k_bscan(const int* __restrict__ bcnt, int* __restrict__ boffs,
                                               int* __restrict__ bcur) {
    __shared__ int sm[256];
    int t = threadIdx.x;
    int4 v = *(const int4*)&bcnt[t * 4];
    int tsum = v.x + v.y + v.z + v.w;
    sm[t] = tsum;
    __syncthreads();
    for (int off = 1; off < 256; off <<= 1) {
        int val = sm[t];
        int add = (t >= off) ? sm[t - off] : 0;
        __syncthreads();
        sm[t] = val + add;
        __syncthreads();
    }
    int excl = sm[t] - tsum;
    int o0 = excl, o1 = excl + v.x, o2 = o1 + v.y, o3 = o2 + v.z;
    boffs[t * 4] = o0; boffs[t * 4 + 1] = o1; boffs[t * 4 + 2] = o2; boffs[t * 4 + 3] = o3;
    bcur[t * 4] = o0;  bcur[t * 4 + 1] = o1;  bcur[t * 4 + 2] = o2;  bcur[t * 4 + 3] = o3;
}

// ---------------- pass C: bin edges into per-bucket packed segments (two-pass per block) ----------------
// packed entry: (src << 7) | (dst & 127)   [src < 2^17]
__global__ __launch_bounds__(256) void k_bin(const int* __restrict__ src, const int* __restrict__ dst,
                                             int* __restrict__ bcur, unsigned int* __restrict__ pairs) {
    __shared__ int lhist[NBUCK];
    __shared__ int lbase[NBUCK];
    int t = threadIdx.x;
    for (int i = t; i < NBUCK; i += 256) lhist[i] = 0;
    __syncthreads();
    int base = blockIdx.x * EPB;
    int lim = min(base + EPB, N_EDGES);
    // pass A: per-block bucket histogram
    for (int e = base + t; e < lim; e += 256)
        atomicAdd(&lhist[dst[e] >> 7], 1);
    __syncthreads();
    // reserve global segment space per bucket; reset counters
    for (int i = t; i < NBUCK; i += 256) {
        int h = lhist[i];
        lbase[i] = h ? atomicAdd(&bcur[i], h) : 0;
        lhist[i] = 0;
    }
    __syncthreads();
    // pass B: scatter (mostly full-line writes: ~16 edges/bucket/block)
    for (int e = base + t; e < lim; e += 256) {
        int d = dst[e];
        int b = d >> 7;
        int r = atomicAdd(&lhist[b], 1);
        pairs[lbase[b] + r] = ((unsigned int)src[e] << 7) | ((unsigned int)d & 127u);
    }
}

// ---------------- pass D: per-bucket CSR fill + deg/offs/dinv (all local, no global scan) ----------------
__global__ __launch_bounds__(256) void k_bfill(const unsigned int* __restrict__ pairs,
                                               const int* __restrict__ boffs,
                                               int* __restrict__ offs, int* __restrict__ deg,
                                               float* __restrict__ dinv, int* __restrict__ perm) {
    __shared__ int lcur[128];
    __shared__ int lsc[128];
    __shared__ int loff[128];
    int b = blockIdx.x;
    int t = threadIdx.x;
    if (t < 128) lcur[t] = 0;
    __syncthreads();
    int p0 = boffs[b];
    int p1 = (b == NBUCK - 1) ? N_EDGES : boffs[b + 1];
    // pass 1: local degree histogram
    for (int p = p0 + t; p < p1; p += 256)
        atomicAdd(&lcur[pairs[p] & 127u], 1);
    __syncthreads();
    if (t < 128) lsc[t] = lcur[t];
    __syncthreads();
    // Hillis-Steele inclusive scan over 128 counts
    for (int off = 1; off < 128; off <<= 1) {
        int val = 0, add = 0;
        if (t < 128) { val = lsc[t]; add = (t >= off) ? lsc[t - off] : 0; }
        __syncthreads();
        if (t < 128) lsc[t] = val + add;
        __syncthreads();
    }
    if (t < 128) {
        int cnt = lcur[t];
        int excl = lsc[t] - cnt + p0;
        loff[t] = excl;
        int node = (b << 7) + t;
        if (node < N_NODES) {
            offs[node] = excl;
            deg[node] = cnt;
            dinv[node] = rsqrtf((float)(cnt + 1));
        }
        lcur[t] = 0;
    }
    __syncthreads();
    // pass 2: place edges (segment is L2-hot)
    for (int p = p0 + t; p < p1; p += 256) {
        unsigned int e = pairs[p];
        int local = (int)(e & 127u);
        int r = atomicAdd(&lcur[local], 1);
        perm[loff[local] + r] = (int)(e >> 7);
    }
}

// ---------------- GEMM: Y_bf16[nrows,128] = X[nrows,128] @ W[128,128] ----------------
template <int BF16IN>
__global__ __launch_bounds__(256) void k_gemm(const void* __restrict__ Xv, const float* __restrict__ W,
                                              unsigned int* __restrict__ Yb, int nrows) {
    __shared__ float xsT[128 * 64];  // [k][r]
    int row0 = blockIdx.x * 64;
    int t = threadIdx.x;
    {
        int r = t >> 2, q = t & 3;
        int grow = row0 + r;
        bool ok = grow < nrows;
        if (BF16IN) {
            const uint2* srcp = (const uint2*)((const unsigned int*)Xv + (size_t)grow * 64 + q * 16);
            #pragma unroll
            for (int i = 0; i < 8; ++i) {
                uint2 u = ok ? srcp[i] : make_uint2(0, 0);
                int c = q * 32 + i * 4;
                xsT[(c + 0) * 64 + r] = bflo(u.x);
                xsT[(c + 1) * 64 + r] = bfhi(u.x);
                xsT[(c + 2) * 64 + r] = bflo(u.y);
                xsT[(c + 3) * 64 + r] = bfhi(u.y);
            }
        } else {
            const float4* srcp = (const float4*)((const float*)Xv + (size_t)grow * CH + q * 32);
            #pragma unroll
            for (int i = 0; i < 8; ++i) {
                float4 v = ok ? srcp[i] : make_float4(0.f, 0.f, 0.f, 0.f);
                int c = q * 32 + i * 4;
                xsT[(c + 0) * 64 + r] = v.x;
                xsT[(c + 1) * 64 + r] = v.y;
                xsT[(c + 2) * 64 + r] = v.z;
                xsT[(c + 3) * 64 + r] = v.w;
            }
        }
    }
    __syncthreads();
    int tx = t & 15, ty = t >> 4;
    float acc[4][8];
    #pragma unroll
    for (int i = 0; i < 4; ++i)
        #pragma unroll
        for (int j = 0; j < 8; ++j) acc[i][j] = 0.f;

    const float4* xs4 = (const float4*)xsT;
    #pragma unroll 4
    for (int k = 0; k < 128; ++k) {
        float4 a = xs4[k * 16 + ty];
        float4 w0 = *(const float4*)&W[k * CH + tx * 8];
        float4 w1 = *(const float4*)&W[k * CH + tx * 8 + 4];
        float av[4] = {a.x, a.y, a.z, a.w};
        float wv[8] = {w0.x, w0.y, w0.z, w0.w, w1.x, w1.y, w1.z, w1.w};
        #pragma unroll
        for (int i = 0; i < 4; ++i)
            #pragma unroll
            for (int j = 0; j < 8; ++j) acc[i][j] += av[i] * wv[j];
    }
    #pragma unroll
    for (int i = 0; i < 4; ++i) {
        int grow = row0 + ty * 4 + i;
        if (grow < nrows) {
            unsigned int o[4];
            #pragma unroll
            for (int j = 0; j < 4; ++j) o[j] = pack2bf(acc[i][2 * j], acc[i][2 * j + 1]);
            *(uint4*)&Yb[(size_t)grow * 64 + tx * 4] = *(uint4*)o;
        }
    }
}

// ---------------- SpMM gather core: 4 edge-slots x 16 lanes, 4x unrolled uint4 loads ----------------
#define ACC8(f, v)                                                                     \
    acc[0] += f * bflo(v.x); acc[1] += f * bfhi(v.x);                                  \
    acc[2] += f * bflo(v.y); acc[3] += f * bfhi(v.y);                                  \
    acc[4] += f * bflo(v.z); acc[5] += f * bfhi(v.z);                                  \
    acc[6] += f * bflo(v.w); acc[7] += f * bfhi(v.w);

#define SPMM_GATHER()                                                                  \
    int w = threadIdx.x >> 6;                                                          \
    int row = __builtin_amdgcn_readfirstlane(blockIdx.x * 4 + w);                      \
    int lane = threadIdx.x & 63;                                                       \
    int g = lane >> 4, c = lane & 15;                                                  \
    float di = dinv[row];                                                              \
    float acc[8];                                                                      \
    _Pragma("unroll") for (int i = 0; i < 8; ++i) acc[i] = 0.f;                        \
    int beg = offs[row], end = beg + deg[row];                                         \
    int j = beg + g;                                                                   \
    for (; j + 12 < end; j += 16) {                                                    \
        int s0 = perm[j], s1 = perm[j + 4], s2 = perm[j + 8], s3 = perm[j + 12];       \
        float f0 = dinv[s0], f1 = dinv[s1], f2 = dinv[s2], f3 = dinv[s3];              \
        uint4 v0 = xw4[(size_t)s0 * 16 + c];                                           \
        uint4 v1 = xw4[(size_t)s1 * 16 + c];                                           \
        uint4 v2 = xw4[(size_t)s2 * 16 + c];                                           \
        uint4 v3 = xw4[(size_t)s3 * 16 + c];                                           \
        f0 *= di; f1 *= di; f2 *= di; f3 *= di;                                        \
        ACC8(f0, v0) ACC8(f1, v1) ACC8(f2, v2) ACC8(f3, v3)                            \
    }                                                                                  \
    for (; j + 4 < end; j += 8) {                                                      \
        int s0 = perm[j], s1 = perm[j + 4];                                            \
        float f0 = di * dinv[s0], f1 = di * dinv[s1];                                  \
        uint4 v0 = xw4[(size_t)s0 * 16 + c];                                           \
        uint4 v1 = xw4[(size_t)s1 * 16 + c];                                           \
        ACC8(f0, v0) ACC8(f1, v1)                                                      \
    }                                                                                  \
    if (j < end) {                                                                     \
        int s = perm[j];                                                               \
        float f = di * dinv[s];                                                        \
        uint4 v = xw4[(size_t)s * 16 + c];                                             \
        ACC8(f, v)                                                                     \
    }                                                                                  \
    _Pragma("unroll") for (int i = 0; i < 8; ++i) {                                    \
        acc[i] += __shfl_xor(acc[i], 16, 64);                                          \
        acc[i] += __shfl_xor(acc[i], 32, 64);                                          \
    }

// ---------------- SpMM layer 1: aggregate + bias + BN + ReLU -> bf16 ----------------
__global__ __launch_bounds__(256) void k_spmm_bn_relu(
    const uint4* __restrict__ xw4, const int* __restrict__ perm, const int* __restrict__ offs,
    const int* __restrict__ deg, const float* __restrict__ dinv, const float* __restrict__ bias,
    const float* __restrict__ gamma, const float* __restrict__ beta,
    const float* __restrict__ rmean, const float* __restrict__ rvar, uint4* __restrict__ outb) {
    SPMM_GATHER()
    if (g == 0) {
        uint4 v = xw4[(size_t)row * 16 + c];
        float sd = di * di;
        ACC8(sd, v)
        int ch = c * 8;
        float r[8];
        #pragma unroll
        for (int i = 0; i < 8; ++i) {
            float sc = gamma[ch + i] * rsqrtf(rvar[ch + i] + BN_EPS);
            r[i] = fmaxf((acc[i] + bias[ch + i] - rmean[ch + i]) * sc + beta[ch + i], 0.f);
        }
        uint4 o;
        o.x = pack2bf(r[0], r[1]); o.y = pack2bf(r[2], r[3]);
        o.z = pack2bf(r[4], r[5]); o.w = pack2bf(r[6], r[7]);
        outb[(size_t)row * 16 + c] = o;
    }
}

// ---------------- SpMM layer 2: aggregate + bias + pooled-sum (block-reduced atomics) ----------------
__global__ __launch_bounds__(256) void k_spmm_pool(
    const uint4* __restrict__ xw4, const int* __restrict__ perm, const int* __restrict__ offs,
    const int* __restrict__ deg, const float* __restrict__ dinv, const float* __restrict__ bias,
    const int* __restrict__ batch, float* __restrict__ psum, int* __restrict__ pcnt) {
    __shared__ float red[4][128];
    __shared__ int gid[4];
    SPMM_GATHER()
    if (g == 0) {
        uint4 v = xw4[(size_t)row * 16 + c];
        float sd = di * di;
        ACC8(sd, v)
        int ch = c * 8;
        #pragma unroll
        for (int i = 0; i < 8; ++i) red[w][ch + i] = acc[i] + bias[ch + i];
    }
    if (lane == 0) gid[w] = batch[row];
    __syncthreads();
    bool same = (gid[0] == gid[1]) && (gid[1] == gid[2]) && (gid[2] == gid[3]);
    int c0 = lane * 2;
    if (same) {
        if (w == 0) {
            float sx = red[0][c0] + red[1][c0] + red[2][c0] + red[3][c0];
            float sy = red[0][c0 + 1] + red[1][c0 + 1] + red[2][c0 + 1] + red[3][c0 + 1];
            unsafeAtomicAdd(&psum[gid[0] * CH + c0], sx);
            unsafeAtomicAdd(&psum[gid[0] * CH + c0 + 1], sy);
            if (lane == 0) atomicAdd(&pcnt[gid[0]], 4);
        }
    } else {
        unsafeAtomicAdd(&psum[gid[w] * CH + c0], red[w][c0]);
        unsafeAtomicAdd(&psum[gid[w] * CH + c0 + 1], red[w][c0 + 1]);
        if (lane == 0) atomicAdd(&pcnt[gid[w]], 1);
    }
}

// ---------------- head: pooled mean -> FC(relu) -> classifier ----------------
__global__ __launch_bounds__(128) void k_head(const float* __restrict__ psum, const int* __restrict__ pcnt,
                                              const float* __restrict__ fw1, const float* __restrict__ fb1,
                                              const float* __restrict__ cw, const float* __restrict__ cb,
                                              float* __restrict__ out) {
    __shared__ float fws[128 * 64];
    for (int i = threadIdx.x; i < 128 * 64; i += 128) fws[i] = fw1[i];
    __syncthreads();
    int g = threadIdx.x;
    float z[64];
    #pragma unroll
    for (int j = 0; j < 64; ++j) z[j] = fb1[j];
    float cnt = fmaxf((float)pcnt[g], 1.f);
    float inv = 1.f / cnt;
    for (int c = 0; c < 128; ++c) {
        float p = psum[g * CH + c] * inv;
        #pragma unroll
        for (int j = 0; j < 64; ++j) z[j] += p * fws[c * 64 + j];
    }
    float o0 = cb[0], o1 = cb[1];
    #pragma unroll
    for (int j = 0; j < 64; ++j) {
        float zz = fmaxf(z[j], 0.f);
        o0 += zz * cw[j * 2];
        o1 += zz * cw[j * 2 + 1];
    }
    out[g * 2] = o0;
    out[g * 2 + 1] = o1;
}

extern "C" void kernel_launch(void* const* d_in, const int* in_sizes, int n_in,
                              void* d_out, int out_size, void* d_ws, size_t ws_size,
                              hipStream_t stream) {
    const float* x     = (const float*)d_in[0];
    const int*   ei    = (const int*)d_in[1];
    const int*   batch = (const int*)d_in[2];
    const float* W1    = (const float*)d_in[3];
    const float* b1    = (const float*)d_in[4];
    const float* gamma = (const float*)d_in[5];
    const float* beta  = (const float*)d_in[6];
    const float* rmean = (const float*)d_in[7];
    const float* rvar  = (const float*)d_in[8];
    const float* W2    = (const float*)d_in[9];
    const float* b2    = (const float*)d_in[10];
    const float* fw1   = (const float*)d_in[11];
    const float* fb1   = (const float*)d_in[12];
    const float* cw    = (const float*)d_in[13];
    const float* cb    = (const float*)d_in[14];
    const int* srcp = ei;
    const int* dstp = ei + N_EDGES;

    char* w = (char*)d_ws;
    // zeroed region first
    int*   bcnt  = (int*)w;   w += 4096;
    float* psum  = (float*)w; w += 65536;
    int*   pcnt  = (int*)w;   w += 512;
    size_t zbytes = 4096 + 65536 + 512;
    // non-zeroed
    int*   deg   = (int*)w;   w += 400000;
    int*   offs  = (int*)w;   w += 400000;
    float* dinv  = (float*)w; w += 400000;
    int*   boffs = (int*)w;   w += 4096;
    int*   bcur  = (int*)w;   w += 4096;
    unsigned int* pairs = (unsigned int*)w; w += 12800000;
    int*   perm  = (int*)w;   w += 12800000;
    unsigned int* bufA = (unsigned int*)w; w += 25600000;  // bf16x2 [100k,64]
    unsigned int* bufB = (unsigned int*)w; w += 25600000;  // bf16x2 [100k,64]

    hipMemsetAsync(d_ws, 0, zbytes, stream);
    k_bhist<<<200, 256, 0, stream>>>(dstp, bcnt);
    k_bscan<<<1, 256, 0, stream>>>(bcnt, boffs, bcur);
    k_bin<<<(N_EDGES + EPB - 1) / EPB, 256, 0, stream>>>(srcp, dstp, bcur, pairs);
    k_bfill<<<NBUCK, 256, 0, stream>>>(pairs, boffs, offs, deg, dinv, perm);
    k_gemm<0><<<1563, 256, 0, stream>>>(x, W1, bufA, N_NODES);
    k_spmm_bn_relu<<<25000, 256, 0, stream>>>((const uint4*)bufA, perm, offs, deg, dinv, b1, gamma, beta, rmean, rvar, (uint4*)bufB);
    k_gemm<1><<<1563, 256, 0, stream>>>(bufB, W2, bufA, N_NODES);
    k_spmm_pool<<<25000, 256, 0, stream>>>((const uint4*)bufA, perm, offs, deg, dinv, b2, batch, psum, pcnt);
    k_head<<<1, 128, 0, stream>>>(psum, pcnt, fw1, fb1, cw, cb, (float*)d_out);
}